// Round 10
// baseline (301.254 us; speedup 1.0000x reference)
//
#include <hip/hip_runtime.h>
#include <stdint.h>

typedef unsigned short u16;
typedef unsigned int u32;

using bf16x8 = __attribute__((ext_vector_type(8))) short;
using f32x4  = __attribute__((ext_vector_type(4))) float;

#define DEVINL __device__ __forceinline__

DEVINL float b2f(u16 u) { return __builtin_bit_cast(float, (u32)u << 16); }
DEVINL u16 f2b(float f) {
  u32 u = __builtin_bit_cast(u32, f);
  u += 0x7FFFu + ((u >> 16) & 1u);   // round-to-nearest-even
  return (u16)(u >> 16);
}

DEVINL void gll16(const u16* src, u16* dst) {
  __builtin_amdgcn_global_load_lds(
      (const __attribute__((address_space(1))) void*)(uintptr_t)src,
      (__attribute__((address_space(3))) void*)(uintptr_t)dst, 16, 0, 0);
}

#define MFMA __builtin_amdgcn_mfma_f32_16x16x32_bf16
#define NROLE 6
#define PROWS 33152          // 518 * 64 (padded row space)
#define PBLK  518

// ---------------------------------------------------------------- role_count
__global__ __launch_bounds__(256) void role_count(
    const int* __restrict__ rid, int* __restrict__ blkCnt)
{
  __shared__ int h[NROLE];
  if (threadIdx.x < NROLE) h[threadIdx.x] = 0;
  __syncthreads();
  atomicAdd(&h[rid[blockIdx.x * 256 + threadIdx.x]], 1);
  __syncthreads();
  if (threadIdx.x < NROLE) blkCnt[blockIdx.x * NROLE + threadIdx.x] = h[threadIdx.x];
}

// ---------------------------------------------------------------- fill2: scan + fill into PADDED bucket space
__global__ __launch_bounds__(256) void fill2(
    const int* __restrict__ rid, const int* __restrict__ blkCnt,
    int* __restrict__ bucket, int* __restrict__ pbaseOut, int* __restrict__ cntArr)
{
  __shared__ int c[128 * NROLE];
  __shared__ int preArr[NROLE], scnt[NROLE], pb[NROLE + 1], h[NROLE];
  const int tid = threadIdx.x;
  const int bx = blockIdx.x;
  for (int i = tid; i < 128 * NROLE; i += 256) c[i] = blkCnt[i];
  if (tid < NROLE) h[tid] = 0;
  __syncthreads();
  if (tid < NROLE) {
    int k = tid, run = 0, pre = 0;
    for (int b = 0; b < 128; ++b) { if (b == bx) pre = run; run += c[b * NROLE + k]; }
    scnt[k] = run; preArr[k] = pre;
  }
  __syncthreads();
  if (tid == 0) {
    pb[0] = 0;
    for (int k = 0; k < NROLE; ++k) pb[k + 1] = pb[k] + ((scnt[k] + 63) & ~63);
  }
  __syncthreads();
  if (bx == 0) {
    if (tid <= NROLE) pbaseOut[tid] = pb[tid];
    if (tid < NROLE) cntArr[tid] = scnt[tid];
    // pad entries -> row 0 (valid index; tail suppresses their writes)
    for (int k = 0; k < NROLE; ++k)
      for (int p = pb[k] + scnt[k] + tid; p < pb[k + 1]; p += 256) bucket[p] = 0;
    for (int p = pb[NROLE] + tid; p < PROWS; p += 256) bucket[p] = 0;
  }
  int i = bx * 256 + tid;
  int k = rid[i];
  int pos = atomicAdd(&h[k], 1);
  bucket[pb[k] + preArr[k] + pos] = i;
}

// ---------------------------------------------------------------- mega0:
// transposes (0..1151) | obs-LN gather->padded bucket order (1152..3223) | rnn copy (3224..3351)
DEVINL void tp_tile(const float* __restrict__ s, u16* __restrict__ d,
                    int R, int C, int bx, int by, int z)
{
  __shared__ u16 tile[32][33];
  const size_t mstride = (size_t)R * C;
  s += (size_t)z * mstride;
  d += (size_t)z * mstride;
  int r0 = bx * 32, c0 = by * 32;
  int tx = threadIdx.x & 31, ty = threadIdx.x >> 5;
#pragma unroll
  for (int i = 0; i < 32; i += 8)
    tile[ty + i][tx] = f2b(s[(size_t)(r0 + ty + i) * C + (c0 + tx)]);
  __syncthreads();
#pragma unroll
  for (int i = 0; i < 32; i += 8)
    d[(size_t)(c0 + ty + i) * R + (r0 + tx)] = tile[tx][ty + i];
}

__global__ __launch_bounds__(256) void mega0(
    const float* W0, const float* W1, const float* Wr0, const float* Wr1, const float* Wh0,
    u16* W0t, u16* W1t, u16* Wr0t, u16* Wr1t, u16* Wh0t,
    const float* __restrict__ obs, const float* __restrict__ fn_s,
    const float* __restrict__ fn_b, u16* __restrict__ obs_nB,
    const int* __restrict__ bucket,
    const float* __restrict__ rnn, float* __restrict__ outRnn)
{
  int b = blockIdx.x;
  const int tid = threadIdx.x;
  if (b < 1152) {
    if (b < 128)      {            tp_tile(W0, W0t, 256, 512, b % 8,  b / 8, 0); }
    else if (b < 384) { b -= 128;  tp_tile(W1, W1t, 512, 512, b % 16, b / 16, 0); }
    else if (b < 576) { b -= 384;  int t = b / 8;  tp_tile(Wr0, Wr0t, 256, 128, b % 8,  t % 4,  t / 4); }
    else if (b < 960) { b -= 576;  int t = b / 4;  tp_tile(Wr1, Wr1t, 128, 512, b % 4,  t % 16, t / 16); }
    else              { b -= 960;  int t = b / 16; tp_tile(Wh0, Wh0t, 512, 64,  b % 16, t % 2,  t / 2); }
  } else if (b < 1152 + PROWS / 16) {
    b -= 1152;
    const int lane = tid & 63, wave = tid >> 6;
#pragma unroll
    for (int it = 0; it < 4; ++it) {
      int p = b * 16 + wave * 4 + it;
      int g = bucket[p];
      const float* xr = obs + (size_t)g * 256 + lane * 4;
      float x[4] __attribute__((aligned(16)));
      *(float4*)x = *(const float4*)xr;
      float s = 0.f, s2 = 0.f;
#pragma unroll
      for (int q = 0; q < 4; ++q) { s += x[q]; s2 += x[q] * x[q]; }
#pragma unroll
      for (int o = 32; o > 0; o >>= 1) { s += __shfl_xor(s, o, 64); s2 += __shfl_xor(s2, o, 64); }
      float m = s * (1.f / 256.f);
      float v = s2 * (1.f / 256.f) - m * m;
      float inv = rsqrtf(v + 1e-5f);
      u16 yu[4] __attribute__((aligned(8)));
#pragma unroll
      for (int q = 0; q < 4; ++q)
        yu[q] = f2b((x[q] - m) * inv * fn_s[lane * 4 + q] + fn_b[lane * 4 + q]);
      *(uint2*)(obs_nB + (size_t)p * 256 + lane * 4) = *(uint2*)yu;
    }
  } else {
    b -= 1152 + PROWS / 16;
    const float4* src = (const float4*)rnn;
    float4* dst = (float4*)outRnn;
    int base = (b * 256 + tid) * 4;
#pragma unroll
    for (int i = 0; i < 4; ++i) dst[base + i] = src[base + i];
  }
}

// ---------------------------------------------------------------- gemm+LN body (BM=64, 4 waves x 128 cols)
template <int K>
DEVINL void gemm_ln_body(
    const u16* __restrict__ A, const u16* __restrict__ Bt,
    const float* __restrict__ bias, const float* __restrict__ lnsc,
    const float* __restrict__ lnbi, u16* __restrict__ C, int bx)
{
  constexpr int BK = 64, NI = K / BK;
  __shared__ __align__(16) u16 As[2][64 * BK];
  __shared__ float redS[64][4];
  __shared__ float redSS[64][4];
  __shared__ float prm[1536];
  const int tid = threadIdx.x;
  const int rowBase = bx * 64;
  const int lane = tid & 63, wave = tid >> 6;
#pragma unroll
  for (int i = tid; i < 512; i += 256) {
    prm[i] = bias[i]; prm[512 + i] = lnsc[i]; prm[1024 + i] = lnbi[i];
  }
  u32 aOff[2];
#pragma unroll
  for (int r = 0; r < 2; ++r) {
    int row = r * 32 + (tid >> 3);
    aOff[r] = (u32)(rowBase + row) * (u32)K + (u32)(((tid & 7) ^ (row & 7)) * 8);
  }
  const int quad = lane >> 4, lm = lane & 15, l7 = lm & 7;
  const int wn = wave * 128;
  u32 bOff[8];
#pragma unroll
  for (int j = 0; j < 8; ++j)
    bOff[j] = (u32)(wn + j * 16 + lm) * (u32)K + (u32)(quad * 8);

  f32x4 acc[4][8] = {};

#pragma unroll
  for (int r = 0; r < 2; ++r)
    gll16(A + aOff[r], &As[0][r * 2048 + wave * 512]);
  bf16x8 bP[8];
#pragma unroll
  for (int j = 0; j < 8; ++j)
    bP[j] = *(const bf16x8*)(Bt + bOff[j]);
  __syncthreads();

  for (int i = 0; i < NI; ++i) {
    const u16* Ab = As[i & 1];
    if (i + 1 < NI) {
#pragma unroll
      for (int r = 0; r < 2; ++r)
        gll16(A + aOff[r] + (i + 1) * BK, &As[(i + 1) & 1][r * 2048 + wave * 512]);
    }
    bf16x8 bN[8];
#pragma unroll
    for (int j = 0; j < 8; ++j)
      bN[j] = *(const bf16x8*)(Bt + bOff[j] + i * BK + 32);
    bf16x8 af[4];
#pragma unroll
    for (int i2 = 0; i2 < 4; ++i2)
      af[i2] = *(const bf16x8*)&Ab[(i2 * 16 + lm) * 64 + ((quad ^ l7) * 8)];
#pragma unroll
    for (int i2 = 0; i2 < 4; ++i2)
#pragma unroll
      for (int j = 0; j < 8; ++j)
        acc[i2][j] = MFMA(af[i2], bP[j], acc[i2][j], 0, 0, 0);
    if (i + 1 < NI) {
#pragma unroll
      for (int j = 0; j < 8; ++j)
        bP[j] = *(const bf16x8*)(Bt + bOff[j] + (i + 1) * BK);
    }
#pragma unroll
    for (int i2 = 0; i2 < 4; ++i2)
      af[i2] = *(const bf16x8*)&Ab[(i2 * 16 + lm) * 64 + (((quad + 4) ^ l7) * 8)];
#pragma unroll
    for (int i2 = 0; i2 < 4; ++i2)
#pragma unroll
      for (int j = 0; j < 8; ++j)
        acc[i2][j] = MFMA(af[i2], bN[j], acc[i2][j], 0, 0, 0);
    __syncthreads();
  }

#pragma unroll
  for (int i2 = 0; i2 < 4; ++i2) {
#pragma unroll
    for (int r2 = 0; r2 < 4; ++r2) {
      float s = 0.f, ss = 0.f;
#pragma unroll
      for (int j = 0; j < 8; ++j) {
        float v = fmaxf(acc[i2][j][r2] + prm[wn + j * 16 + lm], 0.f);
        acc[i2][j][r2] = v;
        s += v; ss += v * v;
      }
#pragma unroll
      for (int o = 1; o < 16; o <<= 1) { s += __shfl_xor(s, o, 64); ss += __shfl_xor(ss, o, 64); }
      if (lm == 0) {
        int rowL = i2 * 16 + quad * 4 + r2;
        redS[rowL][wave] = s;
        redSS[rowL][wave] = ss;
      }
    }
  }
  __syncthreads();
#pragma unroll
  for (int i2 = 0; i2 < 4; ++i2) {
#pragma unroll
    for (int r2 = 0; r2 < 4; ++r2) {
      int rowL = i2 * 16 + quad * 4 + r2;
      float ts  = redS[rowL][0] + redS[rowL][1] + redS[rowL][2] + redS[rowL][3];
      float tss = redSS[rowL][0] + redSS[rowL][1] + redSS[rowL][2] + redSS[rowL][3];
      float m = ts * (1.f / 512.f);
      float var = tss * (1.f / 512.f) - m * m;
      float inv = rsqrtf(var + 1e-5f);
      size_t base = (size_t)(rowBase + rowL) * 512;
#pragma unroll
      for (int j = 0; j < 8; ++j) {
        int col = wn + j * 16 + lm;
        float y = (acc[i2][j][r2] - m) * inv * prm[512 + col] + prm[1024 + col];
        C[base + col] = f2b(y);
      }
    }
  }
}

// ---------------------------------------------------------------- route0 body: r1 = relu(obs_nB @ Wr0^T + br0)
DEVINL void route0_body(
    const u16* __restrict__ A, const u16* __restrict__ Wr0t,
    const float* __restrict__ br0, u16* __restrict__ r1out,
    const int* __restrict__ pbase, int bx)
{
  constexpr int K = 256, NI = 4;
  __shared__ __align__(16) u16 As0[2][64 * 64];
  const int tid = threadIdx.x;
  const int rowBase = bx * 64;
  if (rowBase >= pbase[NROLE]) return;
  int role = 0;
  while (rowBase >= pbase[role + 1]) ++role;
  const int lane = tid & 63, wave = tid >> 6;
  const int quad = lane >> 4, lm = lane & 15, l7 = lm & 7;
  u32 aOff[2];
#pragma unroll
  for (int r = 0; r < 2; ++r) {
    int row = r * 32 + (tid >> 3);
    aOff[r] = (u32)(rowBase + row) * (u32)K + (u32)(((tid & 7) ^ (row & 7)) * 8);
  }
  const int wn0 = wave * 32;
  const u16* B0 = Wr0t + (size_t)role * 128 * 256;
  u32 bOff[2];
#pragma unroll
  for (int j = 0; j < 2; ++j)
    bOff[j] = (u32)(wn0 + j * 16 + lm) * (u32)K + (u32)(quad * 8);

  f32x4 acc[4][2] = {};
#pragma unroll
  for (int r = 0; r < 2; ++r)
    gll16(A + aOff[r], &As0[0][r * 2048 + wave * 512]);
  bf16x8 bP[2];
#pragma unroll
  for (int j = 0; j < 2; ++j) bP[j] = *(const bf16x8*)(B0 + bOff[j]);
  __syncthreads();

  for (int i = 0; i < NI; ++i) {
    const u16* Ab = As0[i & 1];
    if (i + 1 < NI) {
#pragma unroll
      for (int r = 0; r < 2; ++r)
        gll16(A + aOff[r] + (i + 1) * 64, &As0[(i + 1) & 1][r * 2048 + wave * 512]);
    }
    bf16x8 bN[2];
#pragma unroll
    for (int j = 0; j < 2; ++j) bN[j] = *(const bf16x8*)(B0 + bOff[j] + i * 64 + 32);
    bf16x8 af[4];
#pragma unroll
    for (int i2 = 0; i2 < 4; ++i2)
      af[i2] = *(const bf16x8*)&Ab[(i2 * 16 + lm) * 64 + ((quad ^ l7) * 8)];
#pragma unroll
    for (int i2 = 0; i2 < 4; ++i2)
#pragma unroll
      for (int j = 0; j < 2; ++j)
        acc[i2][j] = MFMA(af[i2], bP[j], acc[i2][j], 0, 0, 0);
    if (i + 1 < NI) {
#pragma unroll
      for (int j = 0; j < 2; ++j) bP[j] = *(const bf16x8*)(B0 + bOff[j] + (i + 1) * 64);
    }
#pragma unroll
    for (int i2 = 0; i2 < 4; ++i2)
      af[i2] = *(const bf16x8*)&Ab[(i2 * 16 + lm) * 64 + (((quad + 4) ^ l7) * 8)];
#pragma unroll
    for (int i2 = 0; i2 < 4; ++i2)
#pragma unroll
      for (int j = 0; j < 2; ++j)
        acc[i2][j] = MFMA(af[i2], bN[j], acc[i2][j], 0, 0, 0);
    __syncthreads();
  }
  float bia[2];
#pragma unroll
  for (int j = 0; j < 2; ++j) bia[j] = br0[role * 128 + wn0 + j * 16 + lm];
#pragma unroll
  for (int i2 = 0; i2 < 4; ++i2) {
#pragma unroll
    for (int r2 = 0; r2 < 4; ++r2) {
      int row = rowBase + i2 * 16 + quad * 4 + r2;
#pragma unroll
      for (int j = 0; j < 2; ++j) {
        int col = wn0 + j * 16 + lm;
        r1out[(size_t)row * 128 + col] = f2b(fmaxf(acc[i2][j][r2] + bia[j], 0.f));
      }
    }
  }
}

// merged dispatch: gemm_ln<256> (blocks 0..517) + route0 (518..1035)
__global__ __launch_bounds__(256, 2) void g256_r0(
    const u16* __restrict__ obs_nB, const u16* __restrict__ W0t,
    const float* __restrict__ b0, const float* __restrict__ ln0s,
    const float* __restrict__ ln0b, u16* __restrict__ bufA,
    const u16* __restrict__ Wr0t, const float* __restrict__ br0,
    u16* __restrict__ r1out, const int* __restrict__ pbase)
{
  if (blockIdx.x < PBLK)
    gemm_ln_body<256>(obs_nB, W0t, b0, ln0s, ln0b, bufA, blockIdx.x);
  else
    route0_body(obs_nB, Wr0t, br0, r1out, pbase, blockIdx.x - PBLK);
}

__global__ __launch_bounds__(256, 2) void gemm512(
    const u16* __restrict__ bufA, const u16* __restrict__ W1t,
    const float* __restrict__ b1, const float* __restrict__ ln1s,
    const float* __restrict__ ln1b, u16* __restrict__ bufB)
{
  gemm_ln_body<512>(bufA, W1t, b1, ln1s, ln1b, bufB, blockIdx.x);
}

// ---------------------------------------------------------------- route1: ea = e + relu(r1 @ Wr1^T + br1)
__global__ __launch_bounds__(256, 2) void route1_k(
    const u16* __restrict__ r1, const u16* __restrict__ Wr1t,
    const float* __restrict__ br1, const u16* __restrict__ e,
    u16* __restrict__ ea, const int* __restrict__ pbase)
{
  constexpr int K = 128, NI = 2;
  __shared__ __align__(16) u16 As[2][64 * 64];
  const int tid = threadIdx.x;
  const int rowBase = blockIdx.x * 64;
  if (rowBase >= pbase[NROLE]) return;
  int role = 0;
  while (rowBase >= pbase[role + 1]) ++role;
  const int lane = tid & 63, wave = tid >> 6;
  const int quad = lane >> 4, lm = lane & 15, l7 = lm & 7;
  u32 aOff[2];
#pragma unroll
  for (int r = 0; r < 2; ++r) {
    int row = r * 32 + (tid >> 3);
    aOff[r] = (u32)(rowBase + row) * (u32)K + (u32)(((tid & 7) ^ (row & 7)) * 8);
  }
  const int wn = wave * 128;
  const u16* B1 = Wr1t + (size_t)role * 512 * 128;
  u32 bOff[8];
#pragma unroll
  for (int j = 0; j < 8; ++j)
    bOff[j] = (u32)(wn + j * 16 + lm) * (u32)K + (u32)(quad * 8);

  f32x4 acc[4][8] = {};
#pragma unroll
  for (int r = 0; r < 2; ++r)
    gll16(r1 + aOff[r], &As[0][r * 2048 + wave * 512]);
  bf16x8 bP[8];
#pragma unroll
  for (int j = 0; j < 8; ++j) bP[j] = *(const bf16x8*)(B1 + bOff[j]);
  __syncthreads();

  for (int i = 0; i < NI; ++i) {
    const u16* Ab = As[i & 1];
    if (i + 1 < NI) {
#pragma unroll
      for (int r = 0; r < 2; ++r)
        gll16(r1 + aOff[r] + (i + 1) * 64, &As[(i + 1) & 1][r * 2048 + wave * 512]);
    }
    bf16x8 bN[8];
#pragma unroll
    for (int j = 0; j < 8; ++j) bN[j] = *(const bf16x8*)(B1 + bOff[j] + i * 64 + 32);
    bf16x8 af[4];
#pragma unroll
    for (int i2 = 0; i2 < 4; ++i2)
      af[i2] = *(const bf16x8*)&Ab[(i2 * 16 + lm) * 64 + ((quad ^ l7) * 8)];
#pragma unroll
    for (int i2 = 0; i2 < 4; ++i2)
#pragma unroll
      for (int j = 0; j < 8; ++j)
        acc[i2][j] = MFMA(af[i2], bP[j], acc[i2][j], 0, 0, 0);
    if (i + 1 < NI) {
#pragma unroll
      for (int j = 0; j < 8; ++j) bP[j] = *(const bf16x8*)(B1 + bOff[j] + (i + 1) * 64);
    }
#pragma unroll
    for (int i2 = 0; i2 < 4; ++i2)
      af[i2] = *(const bf16x8*)&Ab[(i2 * 16 + lm) * 64 + (((quad + 4) ^ l7) * 8)];
#pragma unroll
    for (int i2 = 0; i2 < 4; ++i2)
#pragma unroll
      for (int j = 0; j < 8; ++j)
        acc[i2][j] = MFMA(af[i2], bN[j], acc[i2][j], 0, 0, 0);
    __syncthreads();
  }
  float bia[8];
#pragma unroll
  for (int j = 0; j < 8; ++j) bia[j] = br1[role * 512 + wn + j * 16 + lm];
#pragma unroll
  for (int i2 = 0; i2 < 4; ++i2) {
#pragma unroll
    for (int r2 = 0; r2 < 4; ++r2) {
      size_t row = (size_t)(rowBase + i2 * 16 + quad * 4 + r2);
#pragma unroll
      for (int j = 0; j < 8; ++j) {
        int col = wn + j * 16 + lm;
        float v = fmaxf(acc[i2][j][r2] + bia[j], 0.f) + b2f(e[row * 512 + col]);
        ea[row * 512 + col] = f2b(v);
      }
    }
  }
}

// ---------------------------------------------------------------- head_all: h0 MFMA + 64->32->32 tail + mask
__global__ __launch_bounds__(256, 2) void head_all(
    const u16* __restrict__ ea, const u16* __restrict__ Wh0t,
    const float* __restrict__ bh0,
    const float* __restrict__ Wh1, const float* __restrict__ bh1,
    const float* __restrict__ Wh2, const float* __restrict__ bh2,
    const float* __restrict__ avail, const int* __restrict__ bucket,
    const int* __restrict__ pbase, const int* __restrict__ cntArr,
    float* __restrict__ outLogits)
{
  constexpr int K = 512, NI = 8;
  __shared__ __align__(16) u16 As[2][64 * 64];
  __shared__ u16 h0s[64 * 68];
  __shared__ float h1s[64 * 36];
  const int tid = threadIdx.x;
  const int rowBase = blockIdx.x * 64;
  if (rowBase >= pbase[NROLE]) return;
  int role = 0;
  while (rowBase >= pbase[role + 1]) ++role;
  const int lane = tid & 63, wave = tid >> 6;
  const int quad = lane >> 4, lm = lane & 15, l7 = lm & 7;
  u32 aOff[2];
#pragma unroll
  for (int r = 0; r < 2; ++r) {
    int row = r * 32 + (tid >> 3);
    aOff[r] = (u32)(rowBase + row) * (u32)K + (u32)(((tid & 7) ^ (row & 7)) * 8);
  }
  const int col0 = wave * 16 + lm;
  const u16* B2 = Wh0t + (size_t)role * 64 * 512;
  const u32 bOff = (u32)col0 * (u32)K + (u32)(quad * 8);

  f32x4 acc[4] = {};
#pragma unroll
  for (int r = 0; r < 2; ++r)
    gll16(ea + aOff[r], &As[0][r * 2048 + wave * 512]);
  bf16x8 bP = *(const bf16x8*)(B2 + bOff);
  __syncthreads();

  for (int i = 0; i < NI; ++i) {
    const u16* Ab = As[i & 1];
    if (i + 1 < NI) {
#pragma unroll
      for (int r = 0; r < 2; ++r)
        gll16(ea + aOff[r] + (i + 1) * 64, &As[(i + 1) & 1][r * 2048 + wave * 512]);
    }
    bf16x8 bN = *(const bf16x8*)(B2 + bOff + i * 64 + 32);
    bf16x8 af[4];
#pragma unroll
    for (int i2 = 0; i2 < 4; ++i2)
      af[i2] = *(const bf16x8*)&Ab[(i2 * 16 + lm) * 64 + ((quad ^ l7) * 8)];
#pragma unroll
    for (int i2 = 0; i2 < 4; ++i2)
      acc[i2] = MFMA(af[i2], bP, acc[i2], 0, 0, 0);
    if (i + 1 < NI) bP = *(const bf16x8*)(B2 + bOff + (i + 1) * 64);
#pragma unroll
    for (int i2 = 0; i2 < 4; ++i2)
      af[i2] = *(const bf16x8*)&Ab[(i2 * 16 + lm) * 64 + (((quad + 4) ^ l7) * 8)];
#pragma unroll
    for (int i2 = 0; i2 < 4; ++i2)
      acc[i2] = MFMA(af[i2], bN, acc[i2], 0, 0, 0);
    __syncthreads();
  }
  {
    float b2v = bh0[role * 64 + col0];
#pragma unroll
    for (int i2 = 0; i2 < 4; ++i2)
#pragma unroll
      for (int r2 = 0; r2 < 4; ++r2) {
        int row = i2 * 16 + quad * 4 + r2;
        h0s[row * 68 + col0] = f2b(fmaxf(acc[i2][r2] + b2v, 0.f));
      }
  }
  __syncthreads();

  // tail: thread t -> row r = t>>2, 8 cols n0 = (t&3)*8
  {
    const int r = tid >> 2;
    const int n0 = (tid & 3) * 8;
    const float* W1k = Wh1 + (size_t)role * 64 * 32;
    const float* W2k = Wh2 + (size_t)role * 32 * 32;
    float4 a1a = *(const float4*)(bh1 + role * 32 + n0);
    float4 a1b = *(const float4*)(bh1 + role * 32 + n0 + 4);
#pragma unroll 8
    for (int j = 0; j < 64; ++j) {
      float hj = b2f(h0s[r * 68 + j]);
      float4 wa = *(const float4*)(W1k + j * 32 + n0);
      float4 wb = *(const float4*)(W1k + j * 32 + n0 + 4);
      a1a.x += hj * wa.x; a1a.y += hj * wa.y; a1a.z += hj * wa.z; a1a.w += hj * wa.w;
      a1b.x += hj * wb.x; a1b.y += hj * wb.y; a1b.z += hj * wb.z; a1b.w += hj * wb.w;
    }
    h1s[r * 36 + n0 + 0] = fmaxf(a1a.x, 0.f);
    h1s[r * 36 + n0 + 1] = fmaxf(a1a.y, 0.f);
    h1s[r * 36 + n0 + 2] = fmaxf(a1a.z, 0.f);
    h1s[r * 36 + n0 + 3] = fmaxf(a1a.w, 0.f);
    h1s[r * 36 + n0 + 4] = fmaxf(a1b.x, 0.f);
    h1s[r * 36 + n0 + 5] = fmaxf(a1b.y, 0.f);
    h1s[r * 36 + n0 + 6] = fmaxf(a1b.z, 0.f);
    h1s[r * 36 + n0 + 7] = fmaxf(a1b.w, 0.f);
    __syncthreads();
    float4 a2a = *(const float4*)(bh2 + role * 32 + n0);
    float4 a2b = *(const float4*)(bh2 + role * 32 + n0 + 4);
#pragma unroll 8
    for (int n = 0; n < 32; ++n) {
      float hn = h1s[r * 36 + n];
      float4 wa = *(const float4*)(W2k + n * 32 + n0);
      float4 wb = *(const float4*)(W2k + n * 32 + n0 + 4);
      a2a.x += hn * wa.x; a2a.y += hn * wa.y; a2a.z += hn * wa.z; a2a.w += hn * wa.w;
      a2b.x += hn * wb.x; a2b.y += hn * wb.y; a2b.z += hn * wb.z; a2b.w += hn * wb.w;
    }
    int local = rowBase + r - pbase[role];
    if (local < cntArr[role]) {
      int g = bucket[rowBase + r];
      float4 ava = *(const float4*)(avail + (size_t)g * 32 + n0);
      float4 avb = *(const float4*)(avail + (size_t)g * 32 + n0 + 4);
      float4 oa, ob;
      oa.x = (ava.x > 0.5f) ? a2a.x : -1e10f;
      oa.y = (ava.y > 0.5f) ? a2a.y : -1e10f;
      oa.z = (ava.z > 0.5f) ? a2a.z : -1e10f;
      oa.w = (ava.w > 0.5f) ? a2a.w : -1e10f;
      ob.x = (avb.x > 0.5f) ? a2b.x : -1e10f;
      ob.y = (avb.y > 0.5f) ? a2b.y : -1e10f;
      ob.z = (avb.z > 0.5f) ? a2b.z : -1e10f;
      ob.w = (avb.w > 0.5f) ? a2b.w : -1e10f;
      *(float4*)(outLogits + (size_t)g * 32 + n0) = oa;
      *(float4*)(outLogits + (size_t)g * 32 + n0 + 4) = ob;
    }
  }
}

// ---------------------------------------------------------------- launcher
extern "C" void kernel_launch(void* const* d_in, const int* in_sizes, int n_in,
                              void* d_out, int out_size, void* d_ws, size_t ws_size,
                              hipStream_t stream)
{
  const float* rnn  = (const float*)d_in[0];
  const float* obs  = (const float*)d_in[1];
  const float* avail= (const float*)d_in[3];
  const int*   rid  = (const int*)d_in[4];
  const float* fn_s = (const float*)d_in[5];
  const float* fn_b = (const float*)d_in[6];
  const float* W0   = (const float*)d_in[7];
  const float* b0   = (const float*)d_in[8];
  const float* ln0s = (const float*)d_in[9];
  const float* ln0b = (const float*)d_in[10];
  const float* W1   = (const float*)d_in[11];
  const float* b1   = (const float*)d_in[12];
  const float* ln1s = (const float*)d_in[13];
  const float* ln1b = (const float*)d_in[14];
  const float* Wr0  = (const float*)d_in[15];
  const float* br0  = (const float*)d_in[16];
  const float* Wr1  = (const float*)d_in[17];
  const float* br1  = (const float*)d_in[18];
  const float* Wh0  = (const float*)d_in[19];
  const float* bh0  = (const float*)d_in[20];
  const float* Wh1  = (const float*)d_in[21];
  const float* bh1  = (const float*)d_in[22];
  const float* Wh2  = (const float*)d_in[23];
  const float* bh2  = (const float*)d_in[24];

  char* w = (char*)d_ws;
  auto carve = [&](size_t bytes) { char* p = w; w += (bytes + 255) & ~(size_t)255; return p; };
  u16* obs_nB = (u16*)carve((size_t)PROWS * 256 * 2);  // padded bucket order
  u16* bufA   = (u16*)carve((size_t)PROWS * 512 * 2);  // e0, later ea
  u16* bufB   = (u16*)carve((size_t)PROWS * 512 * 2);  // e
  u16* r1buf  = (u16*)carve((size_t)PROWS * 128 * 2);
  u16* W0t    = (u16*)carve((size_t)512 * 256 * 2);
  u16* W1t    = (u16*)carve((size_t)512 * 512 * 2);
  u16* Wr0t   = (u16*)carve((size_t)6 * 128 * 256 * 2);
  u16* Wr1t   = (u16*)carve((size_t)6 * 512 * 128 * 2);
  u16* Wh0t   = (u16*)carve((size_t)6 * 64 * 512 * 2);
  int* bucket = (int*)carve((size_t)PROWS * 4);
  int* blkCnt = (int*)carve((size_t)128 * NROLE * 4);
  int* pbase  = (int*)carve(256);
  int* cntArr = (int*)carve(256);

  float* outLogits = (float*)d_out + (size_t)1024 * 512;

  role_count<<<128, 256, 0, stream>>>(rid, blkCnt);
  fill2<<<128, 256, 0, stream>>>(rid, blkCnt, bucket, pbase, cntArr);

  // transposes + obs-LN (padded bucket order) + rnn passthrough
  mega0<<<1152 + PROWS / 16 + 128, 256, 0, stream>>>(
      W0, W1, Wr0, Wr1, Wh0, W0t, W1t, Wr0t, Wr1t, Wh0t,
      obs, fn_s, fn_b, obs_nB, bucket, rnn, (float*)d_out);

  // layer0 GEMM+LN and route0 in one dispatch (independent work)
  g256_r0<<<2 * PBLK, 256, 0, stream>>>(obs_nB, W0t, b0, ln0s, ln0b, bufA,
                                        Wr0t, br0, r1buf, pbase);

  // layer1 GEMM+LN -> e
  gemm512<<<PBLK, 256, 0, stream>>>(bufA, W1t, b1, ln1s, ln1b, bufB);

  // route1: ea = e + relu(r1 @ Wr1) -> bufA (reuse)
  route1_k<<<PBLK, 256, 0, stream>>>(r1buf, Wr1t, br1, bufB, bufA, pbase);

  // head: h0 MFMA + tail + mask -> logits
  head_all<<<PBLK, 256, 0, stream>>>(bufA, Wh0t, bh0, Wh1, bh1, Wh2, bh2,
                                     avail, bucket, pbase, cntArr, outLogits);
}